// Round 4
// baseline (1962.254 us; speedup 1.0000x reference)
//
#include <hip/hip_runtime.h>

// LocallyConnected2d: x [64,32,64,64] f32, w [1,64,32,62,62,9] f32 -> out [64,64,62,62] f32
// out[b,o,loc] = sum_{i,k} x[b,i,oh+k/3,ow+k%3] * w[o,i,loc,k]
//
// Round-4: per-thread C-tile = [8 b][8 loc] at ONE o.
//  - stores: 32B loc-runs per (b,o)  -> write amp ~1.8x (L3 merge), not 8x.
//  - weights: per-lane-group distinct (o = lane>>3) -> ds_read_b128 with 8 distinct
//    addrs (full-width LDS use; round-2's same-addr broadcast wasted 8x LDS pipe).
//  - w staged via global_load_lds into lane-linear LDS [k][othr][sub], dbuf, 1 barrier/i.
//  - x per-lane (b-octet) from xT through L1; all 8 waves read identical addrs.

#define OWDIM 62
#define LOCS 3844
#define WSI 34596u      // 62*62*9 floats per (o,i)
#define XM 131072u      // 32*64*64 per-batch elements

__global__ void lc2d_transpose_x(const float* __restrict__ x, float* __restrict__ xT) {
    __shared__ float tile[64][65];
    const int m0 = blockIdx.x * 64;
    const int t = threadIdx.x;
    const int c = t & 63, q = t >> 6;
#pragma unroll
    for (int jj = 0; jj < 16; ++jj) {
        const int b = q * 16 + jj;
        tile[c][b] = x[(size_t)b * XM + (size_t)(m0 + c)];
    }
    __syncthreads();
#pragma unroll
    for (int jj = 0; jj < 16; ++jj) {
        const int m = q * 16 + jj;
        xT[(size_t)(m0 + m) * 64u + (size_t)c] = tile[m][c];
    }
}

__global__ __launch_bounds__(512, 4) void lc2d_main(const float* __restrict__ w,
                                                    const float* __restrict__ xT,
                                                    float* __restrict__ out) {
    // [buf][k][othr=o][sub=l] words; write side is lane-linear (global_load_lds),
    // read side: &Bl[cur][k][o][0..7] -> 2x float4, og*8 words -> 2-way banks (free).
    __shared__ float Bl[2][9][64][8];   // 36 KiB

    const int bid = blockIdx.x;
    const int oh  = bid >> 3;
    const int t8  = bid & 7;
    const int ow0 = (t8 < 7) ? (t8 << 3) : 54;  // last tile overlaps (54..61): no guards
    const int loc0 = oh * OWDIM + ow0;

    const int tid  = threadIdx.x;
    const int lane = tid & 63;
    const int wave = __builtin_amdgcn_readfirstlane(tid >> 6);
    const int bg = lane & 7;        // b-octet index (b = bg*8 + db)
    const int og = lane >> 3;       // o within octet
    const int o  = wave * 8 + og;

    const int othr = tid >> 3;      // 0..63 : o-row this thread stages
    const int sub  = tid & 7;       // loc l this thread stages

    // stage channel i's weights into Bl[buf]: 9 async 4B-per-lane DMAs, no VGPR cost
    auto stage = [&](int buf, int i) {
        const float* src = w + (size_t)(othr * 32 + i) * WSI + (size_t)(loc0 + sub) * 9u;
#pragma unroll
        for (int f = 0; f < 9; ++f) {
            __builtin_amdgcn_global_load_lds(
                (const __attribute__((address_space(1))) unsigned int*)(src + f),
                (__attribute__((address_space(3))) unsigned int*)&Bl[buf][f][wave * 8][0],
                4, 0, 0);
        }
    };

    float acc[8][8];   // [db][l]
#pragma unroll
    for (int a = 0; a < 8; ++a)
#pragma unroll
        for (int l = 0; l < 8; ++l) acc[a][l] = 0.f;

    stage(0, 0);
    __syncthreads();

    int cur = 0;
#pragma unroll 1
    for (int i = 0; i < 32; ++i) {
        if (i < 31) stage(cur ^ 1, i + 1);   // fire next channel's DMAs, overlap compute

#pragma unroll
        for (int r = 0; r < 3; ++r) {
            // B fragment: 24 floats [cc][l] for this (o, i, r)
            float bf[24];
#pragma unroll
            for (int cc = 0; cc < 3; ++cc) {
                *(float4*)&bf[cc * 8]     = *(const float4*)&Bl[cur][r * 3 + cc][o][0];
                *(float4*)&bf[cc * 8 + 4] = *(const float4*)&Bl[cur][r * 3 + cc][o][4];
            }
            const float* xrow = xT + (((size_t)i * 4096u + (size_t)((oh + r) * 64 + ow0)) << 6)
                                   + (size_t)(bg * 8);
            float xa[8], xb[8];
            *(float4*)&xa[0] = *(const float4*)(xrow);
            *(float4*)&xa[4] = *(const float4*)(xrow + 4);
#pragma unroll
            for (int m = 0; m < 10; ++m) {           // x column ow0+m
                float* xc = (m & 1) ? xb : xa;       // fully unrolled -> static
                float* xn = (m & 1) ? xa : xb;
                if (m < 9) {                          // prefetch next column
                    const float* xp = xrow + (size_t)((m + 1) * 64);
                    *(float4*)&xn[0] = *(const float4*)(xp);
                    *(float4*)&xn[4] = *(const float4*)(xp + 4);
                }
#pragma unroll
                for (int cc = 0; cc < 3; ++cc) {
                    const int l = m - cc;             // loc' = m - cc
                    if (l >= 0 && l < 8) {
#pragma unroll
                        for (int db = 0; db < 8; ++db)
                            acc[db][l] = fmaf(bf[cc * 8 + l], xc[db], acc[db][l]);
                    }
                }
            }
        }
        __syncthreads();   // own-wave vmcnt(0) drain + all waves' stage visible
        cur ^= 1;
    }

    // stores: per (b,o) an 8-float loc-run -> 4x float2 (loc0 even -> 8B aligned)
#pragma unroll
    for (int db = 0; db < 8; ++db) {
        float* po = out + (size_t)((bg * 8 + db) * 64 + o) * (size_t)LOCS + (size_t)loc0;
#pragma unroll
        for (int q = 0; q < 4; ++q)
            *(float2*)(po + 2 * q) = make_float2(acc[db][2 * q], acc[db][2 * q + 1]);
    }
}

extern "C" void kernel_launch(void* const* d_in, const int* in_sizes, int n_in,
                              void* d_out, int out_size, void* d_ws, size_t ws_size,
                              hipStream_t stream) {
    const float* x = (const float*)d_in[0];   // 64*32*64*64
    const float* w = (const float*)d_in[1];   // 1*64*32*62*62*9
    float* out = (float*)d_out;               // 64*64*62*62
    float* xT = (float*)d_ws;                 // 32 MiB scratch

    lc2d_transpose_x<<<dim3(XM / 64), dim3(256), 0, stream>>>(x, xT);
    lc2d_main<<<dim3(496), dim3(512), 0, stream>>>(w, xT, out);
}

// Round 5
// 936.142 us; speedup vs baseline: 2.0961x; 2.0961x over previous
//
#include <hip/hip_runtime.h>

// LocallyConnected2d: x [64,32,64,64] f32, w [1,64,32,62,62,9] f32 -> out [64,64,62,62] f32
// out[b,o,loc] = sum_{i,k} x[b,i,oh+k/3,ow+k%3] * w[o,i,loc,k]
//
// Round-5: round-4 dataflow (C-tile [8b][8loc] per o), spill-proof codegen:
//  - every local is a float4 var/array with COMPILE-TIME indices (no ptr-to-local,
//    no punning) -> SROA keeps all state in VGPRs (round-4 spilled: VGPR=64, 5GB scratch).
//  - per-wave self-staged weights via global_load_lds (lane-linear [k][og][l] rows),
//    own dbuf, consumed only by the staging wave -> NO barriers; one vmcnt(0) per
//    channel (pre-drained by compiler's x-load waits -> near-free).
//  - 256-thr blocks (one o-half), grid 992 = 8 XCD chunks x 124: adjacent ow-tiles
//    adjacent-in-time on one XCD -> weight line-overfetch and out partial lines merge in L2.

#define OWDIM 62
#define LOCS 3844
#define WSI 34596u      // 62*62*9 floats per (o,i)
#define XM 131072u      // 32*64*64 per-batch x elements

__device__ __forceinline__ float f4get(const float4 v, int j) {
    return j == 0 ? v.x : j == 1 ? v.y : j == 2 ? v.z : v.w;
}
__device__ __forceinline__ void fma4(float4& a, float s, const float4 x) {
    a.x = fmaf(s, x.x, a.x);
    a.y = fmaf(s, x.y, a.y);
    a.z = fmaf(s, x.z, a.z);
    a.w = fmaf(s, x.w, a.w);
}

__global__ void lc2d_transpose_x(const float* __restrict__ x, float* __restrict__ xT) {
    __shared__ float tile[64][65];
    const int m0 = blockIdx.x * 64;
    const int t = threadIdx.x;
    const int c = t & 63, q = t >> 6;
#pragma unroll
    for (int jj = 0; jj < 16; ++jj) {
        const int b = q * 16 + jj;
        tile[c][b] = x[(size_t)b * XM + (size_t)(m0 + c)];
    }
    __syncthreads();
#pragma unroll
    for (int jj = 0; jj < 16; ++jj) {
        const int m = q * 16 + jj;
        xT[(size_t)(m0 + m) * 64u + (size_t)c] = tile[m][c];
    }
}

__global__ __launch_bounds__(256, 3) void lc2d_main(const float* __restrict__ w,
                                                    const float* __restrict__ xT,
                                                    float* __restrict__ out) {
    // [wave][buf][k][og*8+l] floats; DMA writes lane-linear rows (dest = base+lane*4).
    // read: ds_read_b128 at word og*8 (+4): starts {0,8,16,24} mod 32 -> worst 2-way (free).
    __shared__ float Wl[4][2][9][64];   // 18.4 KiB

    const int bid = blockIdx.x;
    const int t = (bid & 7) * 124 + (bid >> 3);          // XCD chunk swizzle (992=8*124)
    const int ohalf = (t >= 496) ? 1 : 0;                // chunks 0-3: o 0..31, 4-7: o 32..63
    const int rem = t - ohalf * 496;
    const int oh = rem >> 3;
    const int t8 = rem & 7;
    const int ow0 = (t8 < 7) ? (t8 << 3) : 54;           // last tile overlaps: no guards
    const int loc0 = oh * OWDIM + ow0;

    const int lane = threadIdx.x & 63;
    const int wave = __builtin_amdgcn_readfirstlane((int)(threadIdx.x >> 6));
    const int bg = lane & 7;      // b-octet (b = bg*8+db); also staging 'sub' (loc l)
    const int og = lane >> 3;     // o within this wave's octet; also staging 'othr'
    const int o_base = ohalf * 32 + wave * 8;

    // per-lane weight source: (o = o_base+og, loc = loc0+bg), 9 taps contiguous
    const float* wsrc = w + (size_t)(o_base + og) * 32u * WSI + (size_t)(loc0 + bg) * 9u;

    float4 accA[8], accB[8];
#pragma unroll
    for (int l = 0; l < 8; ++l) {
        accA[l] = make_float4(0.f, 0.f, 0.f, 0.f);
        accB[l] = make_float4(0.f, 0.f, 0.f, 0.f);
    }

    // prologue: stage channel 0 into buf 0
#pragma unroll
    for (int f = 0; f < 9; ++f)
        __builtin_amdgcn_global_load_lds(
            (const __attribute__((address_space(1))) unsigned int*)(wsrc + f),
            (__attribute__((address_space(3))) unsigned int*)&Wl[wave][0][f][0], 4, 0, 0);

#pragma unroll 1
    for (int i = 0; i < 32; ++i) {
        const int buf = i & 1;

        // guarantee stage(i) landed before its ds_reads; by now the previous
        // channel's x-load waits already drained it -> near-zero cost.
        asm volatile("s_waitcnt vmcnt(0)" ::: "memory");
        __builtin_amdgcn_sched_barrier(0);

        if (i < 31) {   // fire next channel's 9 DMAs into the other buffer
            const float* s = wsrc + (size_t)(i + 1) * WSI;
#pragma unroll
            for (int f = 0; f < 9; ++f)
                __builtin_amdgcn_global_load_lds(
                    (const __attribute__((address_space(1))) unsigned int*)(s + f),
                    (__attribute__((address_space(3))) unsigned int*)&Wl[wave][buf ^ 1][f][0], 4, 0, 0);
        }
        __builtin_amdgcn_sched_barrier(0);

        const float* wl = &Wl[wave][buf][0][0];
#pragma unroll
        for (int r = 0; r < 3; ++r) {
            float4 wqa[3], wqb[3];   // w[cc][l] halves, static idx
#pragma unroll
            for (int cc = 0; cc < 3; ++cc) {
                wqa[cc] = *(const float4*)(wl + (r * 3 + cc) * 64 + og * 8);
                wqb[cc] = *(const float4*)(wl + (r * 3 + cc) * 64 + og * 8 + 4);
            }
            const float* xb = xT + ((size_t)i * 4096u + (size_t)((oh + r) * 64 + ow0)) * 64u
                                 + (size_t)(bg * 8);
            float4 X[2][2];          // ping-pong column buffer, static idx
            X[0][0] = *(const float4*)(xb);
            X[0][1] = *(const float4*)(xb + 4);
#pragma unroll
            for (int m = 0; m < 10; ++m) {
                if (m < 9) {         // prefetch column m+1
                    const float* xp = xb + (size_t)((m + 1) * 64);
                    X[(m + 1) & 1][0] = *(const float4*)(xp);
                    X[(m + 1) & 1][1] = *(const float4*)(xp + 4);
                }
#pragma unroll
                for (int cc = 0; cc < 3; ++cc) {
                    const int l = m - cc;            // loc' touched by col m at tap-col cc
                    if (l >= 0 && l < 8) {
                        const float ws = (l < 4) ? f4get(wqa[cc], l & 3) : f4get(wqb[cc], l & 3);
                        fma4(accA[l], ws, X[m & 1][0]);
                        fma4(accB[l], ws, X[m & 1][1]);
                    }
                }
            }
        }
    }

    // stores: per (b,o) an 8-float loc run -> 4x float2 (loc0 even -> 8B aligned)
    const int o = o_base + og;
#define ACCV(db, l) ((db) < 4 ? f4get(accA[(l)], (db)) : f4get(accB[(l)], (db) - 4))
#pragma unroll
    for (int db = 0; db < 8; ++db) {
        float* po = out + (size_t)((bg * 8 + db) * 64 + o) * (size_t)LOCS + (size_t)loc0;
        *(float2*)(po + 0) = make_float2(ACCV(db, 0), ACCV(db, 1));
        *(float2*)(po + 2) = make_float2(ACCV(db, 2), ACCV(db, 3));
        *(float2*)(po + 4) = make_float2(ACCV(db, 4), ACCV(db, 5));
        *(float2*)(po + 6) = make_float2(ACCV(db, 6), ACCV(db, 7));
    }
#undef ACCV
}

extern "C" void kernel_launch(void* const* d_in, const int* in_sizes, int n_in,
                              void* d_out, int out_size, void* d_ws, size_t ws_size,
                              hipStream_t stream) {
    const float* x = (const float*)d_in[0];   // 64*32*64*64
    const float* w = (const float*)d_in[1];   // 1*64*32*62*62*9
    float* out = (float*)d_out;               // 64*64*62*62
    float* xT = (float*)d_ws;                 // 32 MiB scratch

    lc2d_transpose_x<<<dim3(XM / 64), dim3(256), 0, stream>>>(x, xT);
    lc2d_main<<<dim3(992), dim3(256), 0, stream>>>(w, xT, out);
}

// Round 6
// 399.387 us; speedup vs baseline: 4.9132x; 2.3439x over previous
//
#include <hip/hip_runtime.h>

// LocallyConnected2d: x [64,32,64,64] f32, w [1,64,32,62,62,9] f32 -> out [64,64,62,62] f32
// out[b,o,loc] = sum_{i,k} x[b,i,oh+k/3,ow+k%3] * w[o,i,loc,k]
//
// Round-6 = round-5 dataflow with the two spill/latency fixes:
//  - __launch_bounds__(256,2): VGPR cap 256 for a ~188-reg live set (r4/r5 spilled at
//    caps 64/84 -> GBs of scratch traffic, VALUBusy 13%).
//  - x loads batched 20-deep per (i,r) (all 10 columns x 2 float4) before the 192 FMAs:
//    ILP hides L1/L2 latency that r5's 1-column ping-pong exposed every 16 cycles.
//  - per-wave self-staged weight dbuf via global_load_lds (lane-linear [k][og*8+l]),
//    no barriers, one near-free vmcnt(0) per channel.
//  - C-tile per thread: [8 b][8 loc] at one o; ds_read_b128 weight frags (2-way banks).

#define OWDIM 62
#define LOCS 3844
#define WSI 34596u      // 62*62*9 floats per (o,i)
#define XM 131072u      // 32*64*64 per-batch x elements

__device__ __forceinline__ float f4get(const float4 v, int j) {
    return j == 0 ? v.x : j == 1 ? v.y : j == 2 ? v.z : v.w;
}
__device__ __forceinline__ void fma4(float4& a, float s, const float4 x) {
    a.x = fmaf(s, x.x, a.x);
    a.y = fmaf(s, x.y, a.y);
    a.z = fmaf(s, x.z, a.z);
    a.w = fmaf(s, x.w, a.w);
}

__global__ void lc2d_transpose_x(const float* __restrict__ x, float* __restrict__ xT) {
    __shared__ float tile[64][65];
    const int m0 = blockIdx.x * 64;
    const int t = threadIdx.x;
    const int c = t & 63, q = t >> 6;
#pragma unroll
    for (int jj = 0; jj < 16; ++jj) {
        const int b = q * 16 + jj;
        tile[c][b] = x[(size_t)b * XM + (size_t)(m0 + c)];
    }
    __syncthreads();
#pragma unroll
    for (int jj = 0; jj < 16; ++jj) {
        const int m = q * 16 + jj;
        xT[(size_t)(m0 + m) * 64u + (size_t)c] = tile[m][c];
    }
}

__global__ __launch_bounds__(256, 2) void lc2d_main(const float* __restrict__ w,
                                                    const float* __restrict__ xT,
                                                    float* __restrict__ out) {
    // [wave][buf][k][og*8+l] floats; DMA writes lane-linear (dest = base + lane*4).
    // reads: b128 at word og*8 (+4) -> 8 distinct addrs, worst 2-way banks (free).
    __shared__ float Wl[4][2][9][64];   // 18.4 KiB

    const int bid = blockIdx.x;
    const int t = (bid & 7) * 124 + (bid >> 3);          // XCD chunk swizzle (992 = 8*124)
    const int ohalf = (t >= 496) ? 1 : 0;
    const int rem = t - ohalf * 496;
    const int oh = rem >> 3;
    const int t8 = rem & 7;
    const int ow0 = (t8 < 7) ? (t8 << 3) : 54;           // last tile overlaps: no guards
    const int loc0 = oh * OWDIM + ow0;

    const int lane = threadIdx.x & 63;
    const int wave = __builtin_amdgcn_readfirstlane((int)(threadIdx.x >> 6));
    const int bg = lane & 7;      // b-octet (b = bg*8+db); staging: loc-sub
    const int og = lane >> 3;     // o within wave's octet;  staging: o-row
    const int o_base = ohalf * 32 + wave * 8;

    // per-lane weight source: (o = o_base+og, loc = loc0+bg), 9 taps contiguous
    const float* wsrc = w + (size_t)(o_base + og) * 32u * WSI + (size_t)(loc0 + bg) * 9u;

    float4 accA[8], accB[8];
#pragma unroll
    for (int l = 0; l < 8; ++l) {
        accA[l] = make_float4(0.f, 0.f, 0.f, 0.f);
        accB[l] = make_float4(0.f, 0.f, 0.f, 0.f);
    }

    // prologue: stage channel 0 into buf 0
#pragma unroll
    for (int f = 0; f < 9; ++f)
        __builtin_amdgcn_global_load_lds(
            (const __attribute__((address_space(1))) unsigned int*)(wsrc + f),
            (__attribute__((address_space(3))) unsigned int*)&Wl[wave][0][f][0], 4, 0, 0);

#pragma unroll 1
    for (int i = 0; i < 32; ++i) {
        const int buf = i & 1;

        // stage(i) was issued a full channel ago; x-loads of i-1 are ~2 r-sections old.
        // This drain is therefore near-free, and guarantees buf[i] is readable.
        asm volatile("s_waitcnt vmcnt(0)" ::: "memory");
        __builtin_amdgcn_sched_barrier(0);

        if (i < 31) {   // fire next channel's 9 DMAs into the other buffer
            const float* s = wsrc + (size_t)(i + 1) * WSI;
#pragma unroll
            for (int f = 0; f < 9; ++f)
                __builtin_amdgcn_global_load_lds(
                    (const __attribute__((address_space(1))) unsigned int*)(s + f),
                    (__attribute__((address_space(3))) unsigned int*)&Wl[wave][buf ^ 1][f][0], 4, 0, 0);
        }
        __builtin_amdgcn_sched_barrier(0);

        const float* wl = &Wl[wave][buf][0][0];
#pragma unroll
        for (int r = 0; r < 3; ++r) {
            // weight frags for this row's 3 taps (LDS, 6x b128)
            float4 wqa[3], wqb[3];
#pragma unroll
            for (int cc = 0; cc < 3; ++cc) {
                wqa[cc] = *(const float4*)(wl + (r * 3 + cc) * 64 + og * 8);
                wqb[cc] = *(const float4*)(wl + (r * 3 + cc) * 64 + og * 8 + 4);
            }
            // x row: ALL 10 columns batched (20 independent dwordx4 -> ILP hides latency)
            const float* xb = xT + ((size_t)i * 4096u + (size_t)((oh + r) * 64 + ow0)) * 64u
                                 + (size_t)(bg * 8);
            float4 Xa[10], Xb[10];
#pragma unroll
            for (int m = 0; m < 10; ++m) {
                Xa[m] = *(const float4*)(xb + (size_t)(m * 64));
                Xb[m] = *(const float4*)(xb + (size_t)(m * 64) + 4);
            }
            // 192 FMAs
#pragma unroll
            for (int m = 0; m < 10; ++m) {
#pragma unroll
                for (int cc = 0; cc < 3; ++cc) {
                    const int l = m - cc;            // loc' hit by col m at tap-col cc
                    if (l >= 0 && l < 8) {
                        const float ws = (l < 4) ? f4get(wqa[cc], l & 3) : f4get(wqb[cc], l & 3);
                        fma4(accA[l], ws, Xa[m]);
                        fma4(accB[l], ws, Xb[m]);
                    }
                }
            }
        }
    }

    // stores: per (b,o) an 8-float loc run -> 4x float2 (loc0 even -> 8B aligned)
    const int o = o_base + og;
#define ACCV(db, l) ((db) < 4 ? f4get(accA[(l)], (db)) : f4get(accB[(l)], (db) - 4))
#pragma unroll
    for (int db = 0; db < 8; ++db) {
        float* po = out + (size_t)((bg * 8 + db) * 64 + o) * (size_t)LOCS + (size_t)loc0;
        *(float2*)(po + 0) = make_float2(ACCV(db, 0), ACCV(db, 1));
        *(float2*)(po + 2) = make_float2(ACCV(db, 2), ACCV(db, 3));
        *(float2*)(po + 4) = make_float2(ACCV(db, 4), ACCV(db, 5));
        *(float2*)(po + 6) = make_float2(ACCV(db, 6), ACCV(db, 7));
    }
#undef ACCV
}

extern "C" void kernel_launch(void* const* d_in, const int* in_sizes, int n_in,
                              void* d_out, int out_size, void* d_ws, size_t ws_size,
                              hipStream_t stream) {
    const float* x = (const float*)d_in[0];   // 64*32*64*64
    const float* w = (const float*)d_in[1];   // 1*64*32*62*62*9
    float* out = (float*)d_out;               // 64*64*62*62
    float* xT = (float*)d_ws;                 // 32 MiB scratch

    lc2d_transpose_x<<<dim3(XM / 64), dim3(256), 0, stream>>>(x, xT);
    lc2d_main<<<dim3(992), dim3(256), 0, stream>>>(w, xT, out);
}